// Round 8
// baseline (390.348 us; speedup 1.0000x reference)
//
#include <hip/hip_runtime.h>
#include <hip/hip_bf16.h>
#include <stdint.h>

#define NB 4
#define BS 4096
#define BH 512

typedef __attribute__((ext_vector_type(8))) short bf16x8;
typedef __attribute__((ext_vector_type(4))) float f32x4;

static __device__ __forceinline__ ushort f2bf(float x) {
    union { float f; uint32_t u; } c; c.f = x;
    uint32_t r = c.u + 0x7FFFu + ((c.u >> 16) & 1u);
    return (ushort)(r >> 16);
}
static __device__ __forceinline__ float bf2f(ushort u) {
    union { uint32_t u; float f; } c; c.u = (uint32_t)u << 16;
    return c.f;
}

// async global -> LDS, 16B per lane. dest = wave-uniform base + lane*16.
static __device__ __forceinline__ void gl16(const void* gptr, void* lptr) {
    __builtin_amdgcn_global_load_lds(
        (const __attribute__((address_space(1))) void*)gptr,
        (__attribute__((address_space(3))) void*)lptr, 16, 0, 0);
}

// ---------------------------------------------------------------------------
// Fused projection GEMMs: z = 0/1/2 -> Q/K/V.  Y = X W^T + b, bf16 out.
// z<2: row-major [M,512]; z==2: transposed vT[b][h][s].
// ---------------------------------------------------------------------------
__global__ __launch_bounds__(256) void proj_kernel(
    const float* __restrict__ Xq, const float* __restrict__ Xk, const float* __restrict__ Xv,
    const float* __restrict__ Wq, const float* __restrict__ bq,
    const float* __restrict__ Wk, const float* __restrict__ bk,
    const float* __restrict__ Wv, const float* __restrict__ bv,
    ushort* __restrict__ qb, ushort* __restrict__ kb, ushort* __restrict__ vT)
{
    const int z = blockIdx.z;
    const float* X    = (z == 0) ? Xq : (z == 1) ? Xk : Xv;
    const float* W    = (z == 0) ? Wq : (z == 1) ? Wk : Wv;
    const float* bias = (z == 0) ? bq : (z == 1) ? bk : bv;
    ushort* out       = (z == 0) ? qb : (z == 1) ? kb : vT;
    const bool TR = (z == 2);

    __shared__ ushort As[128 * 32];
    __shared__ ushort Bs[128 * 32];
    const int tid  = threadIdx.x;
    const int lane = tid & 63;
    const int wave = tid >> 6;
    const int wr = wave >> 1, wc = wave & 1;
    const int bi = blockIdx.y, bj = blockIdx.x;

    f32x4 acc[4][4];
    #pragma unroll
    for (int m = 0; m < 4; m++)
        #pragma unroll
        for (int n = 0; n < 4; n++) acc[m][n] = (f32x4)0.0f;

    const int r  = tid >> 1;
    const int kg = (tid & 1) * 16;
    const int kq = (lane >> 4) * 8;
    const int fr = lane & 15;

    for (int kt = 0; kt < 512; kt += 32) {
        {
            const float* src = X + (size_t)(bi * 128 + r) * 512 + kt + kg;
            ushort tmp[16];
            #pragma unroll
            for (int j = 0; j < 4; j++) {
                float4 v = *reinterpret_cast<const float4*>(src + j * 4);
                tmp[j*4+0] = f2bf(v.x); tmp[j*4+1] = f2bf(v.y);
                tmp[j*4+2] = f2bf(v.z); tmp[j*4+3] = f2bf(v.w);
            }
            ushort* dst = &As[r * 32 + kg];
            *reinterpret_cast<uint4*>(dst)     = *reinterpret_cast<const uint4*>(tmp);
            *reinterpret_cast<uint4*>(dst + 8) = *reinterpret_cast<const uint4*>(tmp + 8);
        }
        {
            const float* src = W + (size_t)(bj * 128 + r) * 512 + kt + kg;
            ushort tmp[16];
            #pragma unroll
            for (int j = 0; j < 4; j++) {
                float4 v = *reinterpret_cast<const float4*>(src + j * 4);
                tmp[j*4+0] = f2bf(v.x); tmp[j*4+1] = f2bf(v.y);
                tmp[j*4+2] = f2bf(v.z); tmp[j*4+3] = f2bf(v.w);
            }
            ushort* dst = &Bs[r * 32 + kg];
            *reinterpret_cast<uint4*>(dst)     = *reinterpret_cast<const uint4*>(tmp);
            *reinterpret_cast<uint4*>(dst + 8) = *reinterpret_cast<const uint4*>(tmp + 8);
        }
        __syncthreads();

        bf16x8 af[4], bf[4];
        #pragma unroll
        for (int m = 0; m < 4; m++)
            af[m] = *reinterpret_cast<const bf16x8*>(&As[(wr*64 + m*16 + fr) * 32 + kq]);
        #pragma unroll
        for (int n = 0; n < 4; n++)
            bf[n] = *reinterpret_cast<const bf16x8*>(&Bs[(wc*64 + n*16 + fr) * 32 + kq]);
        #pragma unroll
        for (int m = 0; m < 4; m++)
            #pragma unroll
            for (int n = 0; n < 4; n++)
                acc[m][n] = __builtin_amdgcn_mfma_f32_16x16x32_bf16(af[m], bf[n], acc[m][n], 0, 0, 0);
        __syncthreads();
    }

    const int fq = lane >> 4;
    #pragma unroll
    for (int n = 0; n < 4; n++) {
        const int col = bj * 128 + wc * 64 + n * 16 + fr;
        const float bv2 = bias[col];
        #pragma unroll
        for (int m = 0; m < 4; m++) {
            const int row0 = bi * 128 + wr * 64 + m * 16 + fq * 4;
            if (TR) {
                const int b = row0 >> 12;
                const int s = row0 & 4095;
                ushort4 pk;
                pk.x = f2bf(acc[m][n][0] + bv2);
                pk.y = f2bf(acc[m][n][1] + bv2);
                pk.z = f2bf(acc[m][n][2] + bv2);
                pk.w = f2bf(acc[m][n][3] + bv2);
                *reinterpret_cast<ushort4*>(&out[((size_t)b * 512 + col) * 4096 + s]) = pk;
            } else {
                #pragma unroll
                for (int j = 0; j < 4; j++)
                    out[(size_t)(row0 + j) * 512 + col] = f2bf(acc[m][n][j] + bv2);
            }
        }
    }
}

// ---------------------------------------------------------------------------
// QK^T 256x256 tiles, 8 waves. e = exp(s*scale), bf16 E to ws + row sums.
// Upper 256-tiles: fp32 zero-fill of attn (final value). XCD row-band swizzle
// keeps Q-slice (2MB) + K (4MB) per-XCD-L2 resident.
// ---------------------------------------------------------------------------
__global__ __launch_bounds__(512) void qk_kernel(const ushort* __restrict__ qb,
                                                 const ushort* __restrict__ kb,
                                                 float* __restrict__ attn,
                                                 ushort* __restrict__ Ews,
                                                 float* __restrict__ stats)
{
    // nwg = 1024; XCD x gets s in [128x,128x+128): b = x>>1, 8 bit rows, all bjt
    const int flat = blockIdx.x + (blockIdx.y << 4) + (blockIdx.z << 8);
    const int s    = (flat & 7) * 128 + (flat >> 3);
    const int bjt = s & 15, bit = (s >> 4) & 15, b = s >> 8;

    float* aout = attn + (size_t)b * BS * BS;
    const int tid = threadIdx.x;

    if (bjt > bit) {  // fully masked 256x256 tile -> fp32 zeros (final value)
        const int r  = tid >> 1;
        const int cg = (tid & 1) * 128;
        float4 z = make_float4(0.f, 0.f, 0.f, 0.f);
        float* dst = aout + (size_t)(bit * 256 + r) * BS + bjt * 256 + cg;
        #pragma unroll
        for (int j = 0; j < 32; j++) reinterpret_cast<float4*>(dst)[j] = z;
        return;
    }

    __shared__ ushort A0[256 * 32], A1[256 * 32];   // 16 KB each
    __shared__ ushort B0[256 * 32], B1[256 * 32];
    __shared__ float red[256][2];
    const int lane = tid & 63;
    const int wave = tid >> 6;
    const int wr = wave >> 1;      // 0..3 -> 64-row slot
    const int wc = wave & 1;       // 0..1 -> 128-col slot

    f32x4 acc[4][8];
    #pragma unroll
    for (int m = 0; m < 4; m++)
        #pragma unroll
        for (int n = 0; n < 8; n++) acc[m][n] = (f32x4)0.0f;

    const ushort* Qb = qb + (size_t)(b * BS + bit * 256) * 512;
    const ushort* Kb = kb + (size_t)(b * BS + bjt * 256) * 512;

    // staging: 16 chunks of 16 rows each for A and B; wave w -> chunks {2w,2w+1}
    const int c0 = wave * 2, c1 = wave * 2 + 1;
    const int glr = lane >> 2;                      // row within chunk
    const int gsw = ((lane & 3) ^ (glr & 3)) * 8;   // inverse-swizzled granule
    const ushort* ga0 = Qb + (size_t)(c0 * 16 + glr) * 512 + gsw;
    const ushort* ga1 = Qb + (size_t)(c1 * 16 + glr) * 512 + gsw;
    const ushort* gb0 = Kb + (size_t)(c0 * 16 + glr) * 512 + gsw;
    const ushort* gb1 = Kb + (size_t)(c1 * 16 + glr) * 512 + gsw;
    ushort* a0l0 = &A0[c0 * 512]; ushort* a0l1 = &A0[c1 * 512];
    ushort* a1l0 = &A1[c0 * 512]; ushort* a1l1 = &A1[c1 * 512];
    ushort* b0l0 = &B0[c0 * 512]; ushort* b0l1 = &B0[c1 * 512];
    ushort* b1l0 = &B1[c0 * 512]; ushort* b1l1 = &B1[c1 * 512];

    const int fr = lane & 15;
    const int fq = lane >> 4;
    const int kqs = (fq ^ (fr & 3)) * 8;   // swizzled read slot

    auto domfma = [&](const ushort* Ab, const ushort* Bb) {
        bf16x8 af[4], bf[8];
        #pragma unroll
        for (int m = 0; m < 4; m++)
            af[m] = *reinterpret_cast<const bf16x8*>(&Ab[(wr*64 + m*16 + fr) * 32 + kqs]);
        #pragma unroll
        for (int n = 0; n < 8; n++)
            bf[n] = *reinterpret_cast<const bf16x8*>(&Bb[(wc*128 + n*16 + fr) * 32 + kqs]);
        __builtin_amdgcn_s_setprio(1);
        #pragma unroll
        for (int m = 0; m < 4; m++)
            #pragma unroll
            for (int n = 0; n < 8; n++)
                acc[m][n] = __builtin_amdgcn_mfma_f32_16x16x32_bf16(af[m], bf[n], acc[m][n], 0, 0, 0);
        __builtin_amdgcn_s_setprio(0);
    };

    // prologue: stage tile 0 into buffers 0
    gl16(ga0, a0l0); gl16(ga1, a0l1);
    gl16(gb0, b0l0); gl16(gb1, b0l1);
    __syncthreads();

    for (int kt = 0; kt < 512; kt += 64) {
        gl16(ga0 + kt + 32, a1l0); gl16(ga1 + kt + 32, a1l1);
        gl16(gb0 + kt + 32, b1l0); gl16(gb1 + kt + 32, b1l1);
        domfma(A0, B0);
        __syncthreads();
        if (kt + 64 < 512) {
            gl16(ga0 + kt + 64, a0l0); gl16(ga1 + kt + 64, a0l1);
            gl16(gb0 + kt + 64, b0l0); gl16(gb1 + kt + 64, b0l1);
        }
        domfma(A1, B1);
        __syncthreads();
    }

    const float scaling = 0.044194173824159216f;  // 1/sqrt(512)
    ushort* Eb = Ews + ((size_t)b << 24);
    const bool diag = (bit == bjt);

    #pragma unroll
    for (int m = 0; m < 4; m++) {
        #pragma unroll
        for (int j = 0; j < 4; j++) {
            const int r_loc = wr * 64 + m * 16 + fq * 4 + j;
            const int grow  = bit * 256 + r_loc;
            float sum = 0.0f;
            #pragma unroll
            for (int n = 0; n < 8; n++) {
                const int col = bjt * 256 + wc * 128 + n * 16 + fr;
                const bool masked = diag && (col > grow);
                float e = masked ? 0.0f : __expf(acc[m][n][j] * scaling);
                Eb[(size_t)grow * BS + col] = f2bf(e);
                sum += e;
            }
            #pragma unroll
            for (int o = 1; o < 16; o <<= 1) sum += __shfl_xor(sum, o);
            if (fr == 0) red[r_loc][wc] = sum;
        }
    }
    __syncthreads();
    if (tid < 256)
        stats[(size_t)(b * 16 + bjt) * 4096 + bit * 256 + tid] = red[tid][0] + red[tid][1];
}

// ---------------------------------------------------------------------------
// Merge per-tile sums into per-row 1/sum AND zero ctx. Grid: 512 x 256.
// ---------------------------------------------------------------------------
__global__ __launch_bounds__(256) void reduce_kernel(const float* __restrict__ stats,
                                                     float* __restrict__ rowstat,
                                                     float4* __restrict__ ctx4)
{
    const int g = blockIdx.x * 256 + threadIdx.x;   // 0..131071
    const float4 z = make_float4(0.f, 0.f, 0.f, 0.f);
    #pragma unroll
    for (int i = 0; i < 16; i++)
        ctx4[(size_t)i * 131072 + g] = z;

    if (g < 16384) {
        const int b = g >> 12, i = g & 4095;
        const int nt = (i >> 8) + 1;
        float S = 0.0f;
        for (int t = 0; t < nt; t++)
            S += stats[(size_t)(b * 16 + t) * 4096 + i];
        rowstat[g] = 1.0f / S;
    }
}

// ---------------------------------------------------------------------------
// PV (ctx only). K-split blocks (batch, 32-row tile, 1024-wide k-chunk).
// Reads bf16 E, p = E*inv -> MFMA with V^T. ctx partials via fp32 atomics.
// ---------------------------------------------------------------------------
__global__ __launch_bounds__(256) void pv_kernel(const ushort* __restrict__ vT,
                                                 const ushort* __restrict__ Ews,
                                                 const float* __restrict__ rowstat,
                                                 float* __restrict__ ctx)
{
    const int b = blockIdx.x & 3;                 // batch -> XCD affinity
    const int f = blockIdx.x >> 2;                // 0..319
    int w = 3;
    if (f < 16 * 1 * 2)      w = 0;
    else if (f < 16 * 2 * 3) w = 1;
    else if (f < 16 * 3 * 4) w = 2;
    const int start = 16 * w * (w + 1);
    const int local = f - start;
    const int bi32  = (w << 5) + local / (w + 1);
    const int ks    = local % (w + 1);

    const int nt = bi32 + 1;
    const int t0 = ks * 32;
    const int t1 = min(nt, (ks + 1) * 32);

    __shared__ ushort Vsh[512 * 32];              // 32 KB
    __shared__ ushort Psh[32 * 40];               // 2.5 KB

    const int tid  = threadIdx.x;
    const int lane = tid & 63;
    const int wave = tid >> 6;
    const int fr = lane & 15;
    const int fq = lane >> 4;
    const int kqs = (fq ^ (fr & 3)) * 8;

    f32x4 acc[2][8];
    #pragma unroll
    for (int m = 0; m < 2; m++)
        #pragma unroll
        for (int n = 0; n < 8; n++) acc[m][n] = (f32x4)0.0f;

    const ushort* Vb = vT + (size_t)b * 512 * BS;

    const int ar   = tid >> 3;
    const int akc  = (tid & 7) * 4;
    const int grow = bi32 * 32 + ar;
    const ushort* Erow = Ews + ((size_t)b << 24) + (size_t)grow * BS;
    const float rinv = rowstat[b * 4096 + grow];

    const int glr = lane >> 2;
    const int gsw = ((lane & 3) ^ (glr & 3)) * 8;
    const ushort* gB[8];
    ushort* lB[8];
    #pragma unroll
    for (int q = 0; q < 8; q++) {
        const int chunk = wave * 8 + q;
        gB[q] = Vb + (size_t)(chunk * 16 + glr) * BS + gsw;
        lB[q] = &Vsh[chunk * 512];
    }

    ushort4 a_cur = *reinterpret_cast<const ushort4*>(Erow + t0 * 32 + akc);

    for (int t = t0; t < t1; t++) {
        const int kt = t * 32;
        #pragma unroll
        for (int q = 0; q < 8; q++) gl16(gB[q] + kt, lB[q]);

        ushort4 a_nxt;
        if (t + 1 < t1) a_nxt = *reinterpret_cast<const ushort4*>(Erow + kt + 32 + akc);

        ushort4 pb;
        pb.x = f2bf(bf2f(a_cur.x) * rinv);
        pb.y = f2bf(bf2f(a_cur.y) * rinv);
        pb.z = f2bf(bf2f(a_cur.z) * rinv);
        pb.w = f2bf(bf2f(a_cur.w) * rinv);
        *reinterpret_cast<ushort4*>(&Psh[ar * 40 + akc]) = pb;
        __syncthreads();

        bf16x8 af[2], bfr[8];
        #pragma unroll
        for (int m = 0; m < 2; m++)
            af[m] = *reinterpret_cast<const bf16x8*>(&Psh[(m * 16 + fr) * 40 + fq * 8]);
        #pragma unroll
        for (int n = 0; n < 8; n++)
            bfr[n] = *reinterpret_cast<const bf16x8*>(&Vsh[(wave * 128 + n * 16 + fr) * 32 + kqs]);
        __builtin_amdgcn_s_setprio(1);
        #pragma unroll
        for (int m = 0; m < 2; m++)
            #pragma unroll
            for (int n = 0; n < 8; n++)
                acc[m][n] = __builtin_amdgcn_mfma_f32_16x16x32_bf16(af[m], bfr[n], acc[m][n], 0, 0, 0);
        __builtin_amdgcn_s_setprio(0);
        __syncthreads();
        a_cur = a_nxt;
    }

    float* Crow = ctx + (size_t)b * BS * 512;
    const bool single = (w == 0);
    #pragma unroll
    for (int n = 0; n < 8; n++) {
        const int col = wave * 128 + n * 16 + fr;
        #pragma unroll
        for (int m = 0; m < 2; m++) {
            const int row0 = bi32 * 32 + m * 16 + fq * 4;
            #pragma unroll
            for (int j = 0; j < 4; j++) {
                float* dst = &Crow[(size_t)(row0 + j) * 512 + col];
                if (single) *dst = acc[m][n][j];
                else        unsafeAtomicAdd(dst, acc[m][n][j]);
            }
        }
    }
}

// ---------------------------------------------------------------------------
// Streaming normalize+store: attn[b][i][0..ceil256(i+1)) = E * rinv.
// (E is 0 above the diagonal inside the diagonal 256-tile -> exact zeros.)
// Upper 256-tiles were zero-filled by qk. Pure-BW kernel.
// ---------------------------------------------------------------------------
__global__ __launch_bounds__(256) void norm_kernel(const ushort* __restrict__ Ews,
                                                   const float* __restrict__ rowstat,
                                                   float* __restrict__ attn)
{
    const long long total = (long long)NB * 4096 * 1024;   // float4 items per full row
    for (long long wk = (long long)blockIdx.x * 256 + threadIdx.x; wk < total;
         wk += (long long)gridDim.x * 256) {
        const int c4 = (int)(wk & 1023);
        const int i  = (int)((wk >> 10) & 4095);
        const int b  = (int)(wk >> 22);
        const int ncols4 = ((i >> 8) + 1) << 6;   // ((i>>8)+1)*256/4
        if (c4 >= ncols4) continue;
        const float rinv = rowstat[b * 4096 + i];
        const ushort4 e = *reinterpret_cast<const ushort4*>(
            Ews + ((size_t)b << 24) + (size_t)i * BS + c4 * 4);
        float4 o;
        o.x = bf2f(e.x) * rinv;
        o.y = bf2f(e.y) * rinv;
        o.z = bf2f(e.z) * rinv;
        o.w = bf2f(e.w) * rinv;
        *reinterpret_cast<float4*>(attn + (size_t)b * BS * BS + (size_t)i * BS + c4 * 4) = o;
    }
}

extern "C" void kernel_launch(void* const* d_in, const int* in_sizes, int n_in,
                              void* d_out, int out_size, void* d_ws, size_t ws_size,
                              hipStream_t stream)
{
    const float* queries = (const float*)d_in[0];
    const float* keys    = (const float*)d_in[1];
    const float* values  = (const float*)d_in[2];
    const float* Wq = (const float*)d_in[3];
    const float* bq = (const float*)d_in[4];
    const float* Wk = (const float*)d_in[5];
    const float* bk = (const float*)d_in[6];
    const float* Wv = (const float*)d_in[7];
    const float* bv = (const float*)d_in[8];

    float* ctx  = (float*)d_out;                         // [B,S,H]
    float* attn = (float*)d_out + (size_t)NB * BS * BH;  // [B,S,S]

    ushort* qb = (ushort*)d_ws;                          // bf16 [B*S, H]
    ushort* kb = qb + (size_t)NB * BS * BH;
    ushort* vT = kb + (size_t)NB * BS * BH;              // bf16 [B][H][S]
    ushort* Ews = vT + (size_t)NB * BH * BS;             // bf16 [B][S][S]
    float*  stats   = (float*)(Ews + (size_t)NB * BS * BS);  // [B][16][4096]
    float*  rowstat = stats + (size_t)NB * 16 * 4096;        // [B][4096]

    dim3 blk(256);
    proj_kernel<<<dim3(4, 128, 3), blk, 0, stream>>>(
        queries, keys, values, Wq, bq, Wk, bk, Wv, bv, qb, kb, vT);

    qk_kernel<<<dim3(16, 16, 4), dim3(512), 0, stream>>>(qb, kb, attn, Ews, stats);

    reduce_kernel<<<dim3(512), blk, 0, stream>>>(stats, rowstat, (float4*)ctx);

    pv_kernel<<<dim3(1280), blk, 0, stream>>>(vT, Ews, rowstat, ctx);

    norm_kernel<<<dim3(2048), blk, 0, stream>>>(Ews, rowstat, attn);
}